// Round 1
// baseline (821.329 us; speedup 1.0000x reference)
//
#include <hip/hip_runtime.h>
#include <hip/hip_bf16.h>
#include <math.h>

// Problem constants (B=4, S=2048 -> T=8192, D=1024, E=8, K=2, H=2048)
#define T_TOK 8192
#define D_DIM 1024
#define E_NUM 8
#define H_DIM 2048

typedef __bf16 bf16;
typedef __bf16 bf16x8 __attribute__((ext_vector_type(8)));
typedef __bf16 bf16x4 __attribute__((ext_vector_type(4)));
typedef float  f32x4  __attribute__((ext_vector_type(4)));

// ---------------------------------------------------------------- cvt_x
// x fp32 -> bf16, 8 elems/thread
__global__ void cvt_x_kernel(const float* __restrict__ x, bf16* __restrict__ xb) {
    int i = blockIdx.x * blockDim.x + threadIdx.x;
    const float4* xp = (const float4*)x;
    float4 a = xp[i * 2];
    float4 b = xp[i * 2 + 1];
    bf16x8 o;
    o[0] = (bf16)a.x; o[1] = (bf16)a.y; o[2] = (bf16)a.z; o[3] = (bf16)a.w;
    o[4] = (bf16)b.x; o[5] = (bf16)b.y; o[6] = (bf16)b.z; o[7] = (bf16)b.w;
    *(bf16x8*)(xb + (size_t)i * 8) = o;
}

// ---------------------------------------------------------------- gating
// One wave (64 lanes) per token. fp64 accumulation so top-2 selection matches
// the numpy reference (a flipped expert would blow the absmax threshold).
__global__ void gating_kernel(const float* __restrict__ x, const float* __restrict__ gw,
                              const float* __restrict__ gb, int* __restrict__ counts,
                              int* __restrict__ eIdx, float* __restrict__ wgt) {
    int token = blockIdx.x * 4 + (threadIdx.x >> 6);
    int lane  = threadIdx.x & 63;
    double acc[E_NUM];
#pragma unroll
    for (int e = 0; e < E_NUM; e++) acc[e] = 0.0;
    const float* xt = x + (size_t)token * D_DIM;
#pragma unroll 4
    for (int i = 0; i < D_DIM / 64; i++) {
        int d = lane + i * 64;
        float xv = xt[d];
        float4 g0 = *(const float4*)(gw + (size_t)d * E_NUM);
        float4 g1 = *(const float4*)(gw + (size_t)d * E_NUM + 4);
        acc[0] += (double)xv * g0.x; acc[1] += (double)xv * g0.y;
        acc[2] += (double)xv * g0.z; acc[3] += (double)xv * g0.w;
        acc[4] += (double)xv * g1.x; acc[5] += (double)xv * g1.y;
        acc[6] += (double)xv * g1.z; acc[7] += (double)xv * g1.w;
    }
#pragma unroll
    for (int off = 32; off > 0; off >>= 1) {
#pragma unroll
        for (int e = 0; e < E_NUM; e++) acc[e] += __shfl_down(acc[e], off);
    }
    if (lane == 0) {
        double v[E_NUM], p[E_NUM];
        double mx = -1e300;
#pragma unroll
        for (int e = 0; e < E_NUM; e++) { v[e] = acc[e] + (double)gb[e]; mx = fmax(mx, v[e]); }
        double sum = 0.0;
#pragma unroll
        for (int e = 0; e < E_NUM; e++) { p[e] = exp(v[e] - mx); sum += p[e]; }
        int i0 = 0; double p0 = p[0];
#pragma unroll
        for (int e = 1; e < E_NUM; e++) if (p[e] > p0) { p0 = p[e]; i0 = e; }
        int i1 = -1; double p1 = -1.0;
#pragma unroll
        for (int e = 0; e < E_NUM; e++) if (e != i0 && p[e] > p1) { p1 = p[e]; i1 = e; }
        double q0 = p0 / sum, q1 = p1 / sum;
        double s = q0 + q1 + 1e-9;
        eIdx[token * 2]     = i0;
        eIdx[token * 2 + 1] = i1;
        wgt[token * 2]      = (float)(q0 / s);
        wgt[token * 2 + 1]  = (float)(q1 / s);
        atomicAdd(&counts[i0], 1);
        atomicAdd(&counts[i1], 1);
    }
}

// ---------------------------------------------------------------- scan
__global__ void scan_kernel(const int* __restrict__ counts, int* __restrict__ offsets) {
    if (threadIdx.x == 0) {
        int s = 0;
        for (int e = 0; e < E_NUM; e++) { offsets[e] = s; s += counts[e]; }
    }
}

// ---------------------------------------------------------------- scatter
__global__ void scatter_kernel(const int* __restrict__ eIdx, const int* __restrict__ offsets,
                               int* __restrict__ fill, int* __restrict__ rowIdx,
                               int* __restrict__ slot) {
    int t = blockIdx.x * blockDim.x + threadIdx.x;
    if (t >= T_TOK) return;
#pragma unroll
    for (int k = 0; k < 2; k++) {
        int e = eIdx[t * 2 + k];
        int pos = atomicAdd(&fill[e], 1);
        int r = offsets[e] + pos;
        rowIdx[r] = t;
        slot[t * 2 + k] = r;
    }
}

// ---------------------------------------------------------------- grouped GEMM
// C[r, n] = act( sum_k A[r, k] * W[e][k, n] + bias[e][n] ), r in expert-e's
// compact row segment. A is bf16 (gathered token rows for GEMM1, compact h rows
// for GEMM2). W fp32 [K,N] transpose-staged into LDS as bf16 [n][k].
// 128x128x32 tile, 4 waves, 4x4 of 16x16x32 MFMA per wave.
template <int KD, int ND, bool RELU, bool GATHER>
__global__ __launch_bounds__(256, 2) void moe_gemm_kernel(
    const bf16* __restrict__ A, const float* __restrict__ Bw,
    const float* __restrict__ bias, bf16* __restrict__ Out,
    const int* __restrict__ counts, const int* __restrict__ offsets,
    const int* __restrict__ rowIdx) {
    const int e  = blockIdx.z;
    const int Ne = counts[e];
    const int rb = blockIdx.y;
    if (rb * 128 >= Ne) return;
    const int base = offsets[e];
    const int n0   = blockIdx.x * 128;
    const float* Be = Bw + (size_t)e * KD * ND;
    const float* be = bias + (size_t)e * ND;

    __shared__ bf16 As[128 * 40];  // [m][k], stride 40 (80B, 16B-aligned rows)
    __shared__ bf16 Bs[128 * 40];  // [n][k]

    const int tid = threadIdx.x;
    // A staging: thread -> (row = tid/2, 16 elems at (tid&1)*16)
    const int ra = tid >> 1;
    const int ha = (tid & 1) * 16;
    int ridx = rb * 128 + ra;
    if (ridx >= Ne) ridx = Ne - 1;  // clamp; extra rows computed but not stored
    const bf16* aptr;
    if (GATHER) aptr = A + (size_t)rowIdx[base + ridx] * KD;
    else        aptr = A + (size_t)(base + ridx) * KD;
    // B staging: thread -> one n column (tid&127), 16 k values at (tid>>7)*16
    const int nb = tid & 127;
    const int kh = (tid >> 7) * 16;
    const float* bcol = Be + n0 + nb;

    const int wave = tid >> 6;
    const int lane = tid & 63;
    const int wm = (wave >> 1) * 64;
    const int wn = (wave & 1) * 64;
    const int lrow = lane & 15;
    const int quad = lane >> 4;

    f32x4 acc[4][4] = {};

    for (int k0 = 0; k0 < KD; k0 += 32) {
        // global loads first (let them overlap)
        bf16x8 a0 = *(const bf16x8*)(aptr + k0 + ha);
        bf16x8 a1 = *(const bf16x8*)(aptr + k0 + ha + 8);
        float bv[16];
#pragma unroll
        for (int i = 0; i < 16; i++) bv[i] = bcol[(size_t)(k0 + kh + i) * ND];
        bf16 tmp[16] __attribute__((aligned(16)));
#pragma unroll
        for (int i = 0; i < 16; i++) tmp[i] = (bf16)bv[i];

        *(bf16x8*)&As[ra * 40 + ha]     = a0;
        *(bf16x8*)&As[ra * 40 + ha + 8] = a1;
        *(bf16x8*)&Bs[nb * 40 + kh]     = *(bf16x8*)&tmp[0];
        *(bf16x8*)&Bs[nb * 40 + kh + 8] = *(bf16x8*)&tmp[8];
        __syncthreads();

        bf16x8 af[4], bfv[4];
#pragma unroll
        for (int t4 = 0; t4 < 4; t4++)
            af[t4] = *(const bf16x8*)&As[(wm + t4 * 16 + lrow) * 40 + quad * 8];
#pragma unroll
        for (int t4 = 0; t4 < 4; t4++)
            bfv[t4] = *(const bf16x8*)&Bs[(wn + t4 * 16 + lrow) * 40 + quad * 8];
#pragma unroll
        for (int ti = 0; ti < 4; ti++)
#pragma unroll
            for (int tj = 0; tj < 4; tj++)
                acc[ti][tj] = __builtin_amdgcn_mfma_f32_16x16x32_bf16(
                    af[ti], bfv[tj], acc[ti][tj], 0, 0, 0);
        __syncthreads();
    }

    // epilogue: C/D layout col = lane&15, row = quad*4 + reg
#pragma unroll
    for (int ti = 0; ti < 4; ti++) {
        int rloc = wm + ti * 16 + quad * 4;
#pragma unroll
        for (int tj = 0; tj < 4; tj++) {
            int gcol = n0 + wn + tj * 16 + lrow;
            float bb = be[gcol];
#pragma unroll
            for (int r = 0; r < 4; r++) {
                int grow = rb * 128 + rloc + r;
                if (grow < Ne) {
                    float v = acc[ti][tj][r] + bb;
                    if (RELU) v = v > 0.f ? v : 0.f;
                    Out[(size_t)(base + grow) * ND + gcol] = (bf16)v;
                }
            }
        }
    }
}

// ---------------------------------------------------------------- combine
// out[t] = w0 * Y[slot0] + w1 * Y[slot1]   (Y rows already include b2)
__global__ void combine_kernel(const bf16* __restrict__ Yb, const int* __restrict__ slot,
                               const float* __restrict__ wgt, float* __restrict__ out) {
    int t = blockIdx.x;
    int d = threadIdx.x * 4;
    int s0 = slot[t * 2], s1 = slot[t * 2 + 1];
    float w0 = wgt[t * 2], w1 = wgt[t * 2 + 1];
    bf16x4 y0 = *(const bf16x4*)(Yb + (size_t)s0 * D_DIM + d);
    bf16x4 y1 = *(const bf16x4*)(Yb + (size_t)s1 * D_DIM + d);
    float4 o;
    o.x = w0 * (float)y0[0] + w1 * (float)y1[0];
    o.y = w0 * (float)y0[1] + w1 * (float)y1[1];
    o.z = w0 * (float)y0[2] + w1 * (float)y1[2];
    o.w = w0 * (float)y0[3] + w1 * (float)y1[3];
    *(float4*)(out + (size_t)t * D_DIM + d) = o;
}

// ---------------------------------------------------------------- launch
extern "C" void kernel_launch(void* const* d_in, const int* in_sizes, int n_in,
                              void* d_out, int out_size, void* d_ws, size_t ws_size,
                              hipStream_t stream) {
    const float* x  = (const float*)d_in[0];
    const float* gw = (const float*)d_in[1];
    const float* gb = (const float*)d_in[2];
    const float* w1 = (const float*)d_in[3];
    const float* b1 = (const float*)d_in[4];
    const float* w2 = (const float*)d_in[5];
    const float* b2 = (const float*)d_in[6];
    float* out = (float*)d_out;

    char* ws = (char*)d_ws;
    // layout (all 16B-aligned):
    //   [0,32)        counts[8]
    //   [32,64)       fill[8]
    //   [64,96)       offsets[8]
    //   [256, +64K)   eIdx   (T*2 int)
    //   +64K          wgt    (T*2 float)
    //   +64K          slot   (T*2 int)
    //   +64K          rowIdx (T*2 int)
    //   @262400       Xb  bf16 T*D        (16 MiB)
    //   @+16777216    Hb  bf16 T*2*H      (64 MiB)
    //   @+67108864    Yb  bf16 T*2*D      (32 MiB)
    int*   counts = (int*)ws;
    int*   fill   = (int*)(ws + 32);
    int*   offs   = (int*)(ws + 64);
    int*   eIdx   = (int*)(ws + 256);
    float* wgt    = (float*)(ws + 256 + 65536);
    int*   slot   = (int*)(ws + 256 + 2 * 65536);
    int*   rowIdx = (int*)(ws + 256 + 3 * 65536);
    bf16*  Xb = (bf16*)(ws + 262400);
    bf16*  Hb = (bf16*)(ws + 262400 + 16777216);
    bf16*  Yb = (bf16*)(ws + 262400 + 16777216 + 67108864);

    if (ws_size < (size_t)(262400 + 16777216 + 67108864 + 33554432)) return;

    hipMemsetAsync(ws, 0, 64, stream);  // counts + fill
    cvt_x_kernel<<<(T_TOK * D_DIM) / (256 * 8), 256, 0, stream>>>(x, Xb);
    gating_kernel<<<T_TOK / 4, 256, 0, stream>>>(x, gw, gb, counts, eIdx, wgt);
    scan_kernel<<<1, 64, 0, stream>>>(counts, offs);
    scatter_kernel<<<T_TOK / 256, 256, 0, stream>>>(eIdx, offs, fill, rowIdx, slot);
    // GEMM1: h = relu(x_gathered @ W1 + b1)   [rows, 2048], K=1024
    moe_gemm_kernel<D_DIM, H_DIM, true, true>
        <<<dim3(H_DIM / 128, T_TOK / 128, E_NUM), 256, 0, stream>>>(
            Xb, w1, b1, Hb, counts, offs, rowIdx);
    // GEMM2: y = h @ W2 + b2   [rows, 1024], K=2048
    moe_gemm_kernel<H_DIM, D_DIM, false, false>
        <<<dim3(D_DIM / 128, T_TOK / 128, E_NUM), 256, 0, stream>>>(
            Hb, w2, b2, Yb, counts, offs, (const int*)nullptr);
    combine_kernel<<<T_TOK, 256, 0, stream>>>(Yb, slot, wgt, out);
}

// Round 2
// 734.517 us; speedup vs baseline: 1.1182x; 1.1182x over previous
//
#include <hip/hip_runtime.h>
#include <hip/hip_bf16.h>
#include <math.h>

// Problem constants (B=4, S=2048 -> T=8192, D=1024, E=8, K=2, H=2048)
#define T_TOK 8192
#define D_DIM 1024
#define E_NUM 8
#define H_DIM 2048

typedef __bf16 bf16;
typedef __bf16 bf16x8 __attribute__((ext_vector_type(8)));
typedef __bf16 bf16x4 __attribute__((ext_vector_type(4)));
typedef float  f32x4  __attribute__((ext_vector_type(4)));

// async global->LDS, 16 B per lane; LDS dest = wave-uniform base + lane*16
__device__ __forceinline__ void gload_lds16(const void* g, void* s) {
    __builtin_amdgcn_global_load_lds(
        (const __attribute__((address_space(1))) unsigned int*)g,
        (__attribute__((address_space(3))) unsigned int*)s, 16, 0, 0);
}

// ---------------------------------------------------------------- cvt_x
__global__ void cvt_x_kernel(const float* __restrict__ x, bf16* __restrict__ xb) {
    int i = blockIdx.x * blockDim.x + threadIdx.x;
    const float4* xp = (const float4*)x;
    float4 a = xp[i * 2];
    float4 b = xp[i * 2 + 1];
    bf16x8 o;
    o[0] = (bf16)a.x; o[1] = (bf16)a.y; o[2] = (bf16)a.z; o[3] = (bf16)a.w;
    o[4] = (bf16)b.x; o[5] = (bf16)b.y; o[6] = (bf16)b.z; o[7] = (bf16)b.w;
    *(bf16x8*)(xb + (size_t)i * 8) = o;
}

// ---------------------------------------------------------------- transpose
// W [E][K][N] fp32  ->  Wt [E][N][K] bf16.  32x32 tiles via LDS.
template <int K, int N>
__global__ void transpose_kernel(const float* __restrict__ W, bf16* __restrict__ Wt) {
    const int e  = blockIdx.z;
    const int kb = blockIdx.y * 32;
    const int nb = blockIdx.x * 32;
    __shared__ float tile[32][33];
    const float* We  = W  + (size_t)e * K * N;
    bf16*        Wte = Wt + (size_t)e * N * K;
    const int tid = threadIdx.x;
    const int r  = tid >> 3;        // 0..31
    const int c4 = (tid & 7) * 4;   // 0..28
    float4 v = *(const float4*)(We + (size_t)(kb + r) * N + nb + c4);
    tile[r][c4 + 0] = v.x; tile[r][c4 + 1] = v.y;
    tile[r][c4 + 2] = v.z; tile[r][c4 + 3] = v.w;
    __syncthreads();
    const int rn = tid >> 3;        // n within tile
    const int k4 = (tid & 7) * 4;   // k within tile
    bf16x4 o;
    o[0] = (bf16)tile[k4 + 0][rn]; o[1] = (bf16)tile[k4 + 1][rn];
    o[2] = (bf16)tile[k4 + 2][rn]; o[3] = (bf16)tile[k4 + 3][rn];
    *(bf16x4*)(Wte + (size_t)(nb + rn) * K + kb + k4) = o;
}

// ---------------------------------------------------------------- gating
// One wave per token, fp64 accumulation (selection must match numpy ref).
__global__ void gating_kernel(const float* __restrict__ x, const float* __restrict__ gw,
                              const float* __restrict__ gb, int* __restrict__ counts,
                              int* __restrict__ eIdx, float* __restrict__ wgt) {
    int token = blockIdx.x * 4 + (threadIdx.x >> 6);
    int lane  = threadIdx.x & 63;
    double acc[E_NUM];
#pragma unroll
    for (int e = 0; e < E_NUM; e++) acc[e] = 0.0;
    const float* xt = x + (size_t)token * D_DIM;
#pragma unroll 4
    for (int i = 0; i < D_DIM / 64; i++) {
        int d = lane + i * 64;
        float xv = xt[d];
        float4 g0 = *(const float4*)(gw + (size_t)d * E_NUM);
        float4 g1 = *(const float4*)(gw + (size_t)d * E_NUM + 4);
        acc[0] += (double)xv * g0.x; acc[1] += (double)xv * g0.y;
        acc[2] += (double)xv * g0.z; acc[3] += (double)xv * g0.w;
        acc[4] += (double)xv * g1.x; acc[5] += (double)xv * g1.y;
        acc[6] += (double)xv * g1.z; acc[7] += (double)xv * g1.w;
    }
#pragma unroll
    for (int off = 32; off > 0; off >>= 1) {
#pragma unroll
        for (int e = 0; e < E_NUM; e++) acc[e] += __shfl_down(acc[e], off);
    }
    if (lane == 0) {
        double v[E_NUM], p[E_NUM];
        double mx = -1e300;
#pragma unroll
        for (int e = 0; e < E_NUM; e++) { v[e] = acc[e] + (double)gb[e]; mx = fmax(mx, v[e]); }
        double sum = 0.0;
#pragma unroll
        for (int e = 0; e < E_NUM; e++) { p[e] = exp(v[e] - mx); sum += p[e]; }
        int i0 = 0; double p0 = p[0];
#pragma unroll
        for (int e = 1; e < E_NUM; e++) if (p[e] > p0) { p0 = p[e]; i0 = e; }
        int i1 = -1; double p1 = -1.0;
#pragma unroll
        for (int e = 0; e < E_NUM; e++) if (e != i0 && p[e] > p1) { p1 = p[e]; i1 = e; }
        double q0 = p0 / sum, q1 = p1 / sum;
        double s = q0 + q1 + 1e-9;
        eIdx[token * 2]     = i0;
        eIdx[token * 2 + 1] = i1;
        wgt[token * 2]      = (float)(q0 / s);
        wgt[token * 2 + 1]  = (float)(q1 / s);
        atomicAdd(&counts[i0], 1);
        atomicAdd(&counts[i1], 1);
    }
}

// ---------------------------------------------------------------- scan
__global__ void scan_kernel(const int* __restrict__ counts, int* __restrict__ offsets) {
    if (threadIdx.x == 0) {
        int s = 0;
        for (int e = 0; e < E_NUM; e++) { offsets[e] = s; s += counts[e]; }
    }
}

// ---------------------------------------------------------------- scatter
__global__ void scatter_kernel(const int* __restrict__ eIdx, const int* __restrict__ offsets,
                               int* __restrict__ fill, int* __restrict__ rowIdx,
                               int* __restrict__ slot) {
    int t = blockIdx.x * blockDim.x + threadIdx.x;
    if (t >= T_TOK) return;
#pragma unroll
    for (int k = 0; k < 2; k++) {
        int e = eIdx[t * 2 + k];
        int pos = atomicAdd(&fill[e], 1);
        int r = offsets[e] + pos;
        rowIdx[r] = t;
        slot[t * 2 + k] = r;
    }
}

// ---------------------------------------------------------------- grouped GEMM
// C[r,n] = act( sum_k A[r,k] * Bt[e][n,k] + bias[e][n] ) on expert-e's compact
// row segment. A bf16 row-major; Bt bf16 [N][K] (pre-transposed weights).
// m97 structure: 128x128x32 tile, global_load_lds dwordx4 staging for A and B,
// 4 waves x 4x4 of 16x16x32 bf16 MFMA.
template <int KD, int ND, bool RELU, bool GATHER>
__global__ __launch_bounds__(256, 2) void moe_gemm_kernel(
    const bf16* __restrict__ A, const bf16* __restrict__ Bt,
    const float* __restrict__ bias, bf16* __restrict__ Out,
    const int* __restrict__ counts, const int* __restrict__ offsets,
    const int* __restrict__ rowIdx) {
    const int e  = blockIdx.z;
    const int Ne = counts[e];
    const int rb = blockIdx.y;
    if (rb * 128 >= Ne) return;
    const int base = offsets[e];
    const int n0   = blockIdx.x * 128;
    const bf16*  Be = Bt + (size_t)e * KD * ND;  // [ND][KD]
    const float* be = bias + (size_t)e * ND;

    __shared__ bf16 As[128 * 32];  // [m][k], unpadded (required by global_load_lds)
    __shared__ bf16 Bs[128 * 32];  // [n][k]

    const int tid  = threadIdx.x;
    const int wave = tid >> 6;
    const int lane = tid & 63;

    // staging map: wave w, issue i covers rows i*64 + w*16 + lane/4,
    // k-chunk (lane&3)*8 elems; LDS dest = base + i*4096 + w*1024 (+lane*16 by HW)
    const int srow  = wave * 16 + (lane >> 2);
    const int skoff = (lane & 3) * 8;
    int m0g = rb * 128 + srow;      if (m0g >= Ne) m0g = Ne - 1;  // clamp: extra rows
    int m1g = rb * 128 + 64 + srow; if (m1g >= Ne) m1g = Ne - 1;  // computed, not stored
    const bf16 *aA0, *aA1;
    if (GATHER) {
        aA0 = A + (size_t)rowIdx[base + m0g] * KD + skoff;
        aA1 = A + (size_t)rowIdx[base + m1g] * KD + skoff;
    } else {
        aA0 = A + (size_t)(base + m0g) * KD + skoff;
        aA1 = A + (size_t)(base + m1g) * KD + skoff;
    }
    const bf16* bB0 = Be + (size_t)(n0 + srow) * KD + skoff;
    const bf16* bB1 = Be + (size_t)(n0 + 64 + srow) * KD + skoff;
    char* dstA0 = (char*)As + wave * 1024;
    char* dstA1 = (char*)As + 4096 + wave * 1024;
    char* dstB0 = (char*)Bs + wave * 1024;
    char* dstB1 = (char*)Bs + 4096 + wave * 1024;

    const int wm = (wave >> 1) * 64;
    const int wn = (wave & 1) * 64;
    const int lrow = lane & 15;
    const int quad = lane >> 4;

    f32x4 acc[4][4] = {};

    for (int k0 = 0; k0 < KD; k0 += 32) {
        gload_lds16(aA0 + k0, dstA0);
        gload_lds16(aA1 + k0, dstA1);
        gload_lds16(bB0 + k0, dstB0);
        gload_lds16(bB1 + k0, dstB1);
        __syncthreads();  // drains vmcnt -> LDS tiles complete

        bf16x8 af[4], bfv[4];
#pragma unroll
        for (int t4 = 0; t4 < 4; t4++)
            af[t4] = *(const bf16x8*)&As[(wm + t4 * 16 + lrow) * 32 + quad * 8];
#pragma unroll
        for (int t4 = 0; t4 < 4; t4++)
            bfv[t4] = *(const bf16x8*)&Bs[(wn + t4 * 16 + lrow) * 32 + quad * 8];
#pragma unroll
        for (int ti = 0; ti < 4; ti++)
#pragma unroll
            for (int tj = 0; tj < 4; tj++)
                acc[ti][tj] = __builtin_amdgcn_mfma_f32_16x16x32_bf16(
                    af[ti], bfv[tj], acc[ti][tj], 0, 0, 0);
        __syncthreads();
    }

    // epilogue: C/D layout col = lane&15, row = quad*4 + reg
#pragma unroll
    for (int ti = 0; ti < 4; ti++) {
        int rloc = wm + ti * 16 + quad * 4;
#pragma unroll
        for (int tj = 0; tj < 4; tj++) {
            int gcol = n0 + wn + tj * 16 + lrow;
            float bb = be[gcol];
#pragma unroll
            for (int r = 0; r < 4; r++) {
                int grow = rb * 128 + rloc + r;
                if (grow < Ne) {
                    float v = acc[ti][tj][r] + bb;
                    if (RELU) v = v > 0.f ? v : 0.f;
                    Out[(size_t)(base + grow) * ND + gcol] = (bf16)v;
                }
            }
        }
    }
}

// ---------------------------------------------------------------- combine
__global__ void combine_kernel(const bf16* __restrict__ Yb, const int* __restrict__ slot,
                               const float* __restrict__ wgt, float* __restrict__ out) {
    int t = blockIdx.x;
    int d = threadIdx.x * 4;
    int s0 = slot[t * 2], s1 = slot[t * 2 + 1];
    float w0 = wgt[t * 2], w1 = wgt[t * 2 + 1];
    bf16x4 y0 = *(const bf16x4*)(Yb + (size_t)s0 * D_DIM + d);
    bf16x4 y1 = *(const bf16x4*)(Yb + (size_t)s1 * D_DIM + d);
    float4 o;
    o.x = w0 * (float)y0[0] + w1 * (float)y1[0];
    o.y = w0 * (float)y0[1] + w1 * (float)y1[1];
    o.z = w0 * (float)y0[2] + w1 * (float)y1[2];
    o.w = w0 * (float)y0[3] + w1 * (float)y1[3];
    *(float4*)(out + (size_t)t * D_DIM + d) = o;
}

// ---------------------------------------------------------------- launch
extern "C" void kernel_launch(void* const* d_in, const int* in_sizes, int n_in,
                              void* d_out, int out_size, void* d_ws, size_t ws_size,
                              hipStream_t stream) {
    const float* x  = (const float*)d_in[0];
    const float* gw = (const float*)d_in[1];
    const float* gb = (const float*)d_in[2];
    const float* w1 = (const float*)d_in[3];
    const float* b1 = (const float*)d_in[4];
    const float* w2 = (const float*)d_in[5];
    const float* b2 = (const float*)d_in[6];
    float* out = (float*)d_out;

    char* ws = (char*)d_ws;
    // layout:
    //   [0,96)            counts[8] / fill[8] / offsets[8]
    //   [256, +4*64K)     eIdx, wgt, slot, rowIdx
    //   @262400           Xb   bf16 T*D               (16 MiB)
    //   @17039616         Hb   bf16 T*2*H             (64 MiB)
    //   @84148480         W2t  bf16 E*D*H             (32 MiB)
    //   @117702912        W1t  bf16 E*H*D  (aliases Yb: W1t dead after GEMM1,
    //                     Yb written by GEMM2)        (32 MiB)
    int*   counts = (int*)ws;
    int*   fill   = (int*)(ws + 32);
    int*   offs   = (int*)(ws + 64);
    int*   eIdx   = (int*)(ws + 256);
    float* wgt    = (float*)(ws + 256 + 65536);
    int*   slot   = (int*)(ws + 256 + 2 * 65536);
    int*   rowIdx = (int*)(ws + 256 + 3 * 65536);
    bf16*  Xb  = (bf16*)(ws + 262400);
    bf16*  Hb  = (bf16*)(ws + 17039616);
    bf16*  W2t = (bf16*)(ws + 84148480);
    bf16*  W1t = (bf16*)(ws + 117702912);
    bf16*  Yb  = W1t;  // alias (see above)

    if (ws_size < (size_t)151257344) return;

    hipMemsetAsync(ws, 0, 64, stream);  // counts + fill
    cvt_x_kernel<<<(T_TOK * D_DIM) / (256 * 8), 256, 0, stream>>>(x, Xb);
    // w1 [E][D][H] -> W1t [E][H][D];  w2 [E][H][D] -> W2t [E][D][H]
    transpose_kernel<D_DIM, H_DIM>
        <<<dim3(H_DIM / 32, D_DIM / 32, E_NUM), 256, 0, stream>>>(w1, W1t);
    transpose_kernel<H_DIM, D_DIM>
        <<<dim3(D_DIM / 32, H_DIM / 32, E_NUM), 256, 0, stream>>>(w2, W2t);
    gating_kernel<<<T_TOK / 4, 256, 0, stream>>>(x, gw, gb, counts, eIdx, wgt);
    scan_kernel<<<1, 64, 0, stream>>>(counts, offs);
    scatter_kernel<<<T_TOK / 256, 256, 0, stream>>>(eIdx, offs, fill, rowIdx, slot);
    // GEMM1: h = relu(x_gathered @ W1 + b1)   [rows, 2048], K=1024
    moe_gemm_kernel<D_DIM, H_DIM, true, true>
        <<<dim3(H_DIM / 128, T_TOK / 128, E_NUM), 256, 0, stream>>>(
            Xb, W1t, b1, Hb, counts, offs, rowIdx);
    // GEMM2: y = h @ W2 + b2   [rows, 1024], K=2048
    moe_gemm_kernel<H_DIM, D_DIM, false, false>
        <<<dim3(D_DIM / 128, T_TOK / 128, E_NUM), 256, 0, stream>>>(
            Hb, W2t, b2, Yb, counts, offs, (const int*)nullptr);
    combine_kernel<<<T_TOK, 256, 0, stream>>>(Yb, slot, wgt, out);
}